// Round 11
// baseline (448.040 us; speedup 1.0000x reference)
//
#include <hip/hip_runtime.h>
#include <hip/hip_bf16.h>

typedef unsigned short u16;
typedef unsigned int u32;
typedef __attribute__((ext_vector_type(8))) short short8;
typedef __attribute__((ext_vector_type(4))) float f32x4;

#define N_LB   4096
#define N_ULB  6144
#define N_TOT  16384
#define D      128
#define C      100
#define CT     104   // classes stored in LT (100 logits + denom@100 + 3 zero)

// d_out element offsets (f32 elements, reference return order)
#define OFF_ANCHOR 0
#define OFF_POS    786432
#define OFF_LBF    1572864
#define OFF_OH     2097152
#define OFF_OUTLB  2506752   // out_lb / out_ulb_1 / out_ulb_2 row-contiguous
#define OFF_SCAL   4145152

__device__ __forceinline__ void split_bf16(float x, u16& hi, u16& lo) {
    __hip_bfloat16 h = __float2bfloat16(x);
    float r = x - __bfloat162float(h);
    __hip_bfloat16 l = __float2bfloat16(r);
    hi = __bfloat16_as_ushort(h);
    lo = __bfloat16_as_ushort(l);
}

// async global->LDS DMA, 16B per lane (wave-uniform LDS base + lane*16)
__device__ __forceinline__ void gl_lds16(const char* g, char* l) {
    __builtin_amdgcn_global_load_lds(
        (const __attribute__((address_space(1))) u32*)g,
        (__attribute__((address_space(3))) u32*)l, 16, 0, 0);
}

// ---------------------------------------------------------------------------
// prep_feats: L2-normalize rows; split to bf16 hi/lo planes in ws
// F2[16384][256] u16 (row = [hi 0..127 | lo 128..255]); exact f32 passthrough.
// ---------------------------------------------------------------------------
__global__ void prep_feats(const float* __restrict__ anchor,
                           const float* __restrict__ positive,
                           const float* __restrict__ lbf,
                           u16* __restrict__ F2,
                           float* __restrict__ out)
{
    const int r = blockIdx.x;
    const int t = threadIdx.x;   // 0..63
    const float* src; int rr, ptbase;
    if (r < N_LB)              { src = lbf;      rr = r;                ptbase = OFF_LBF; }
    else if (r < N_LB + N_ULB) { src = anchor;   rr = r - N_LB;         ptbase = OFF_ANCHOR; }
    else                       { src = positive; rr = r - N_LB - N_ULB; ptbase = OFF_POS; }
    float2 x = *(const float2*)&src[rr * D + 2 * t];
    float ss = x.x * x.x + x.y * x.y;
    #pragma unroll
    for (int m = 32; m; m >>= 1) ss += __shfl_xor(ss, m);
    float inv = 1.0f / fmaxf(sqrtf(ss), 1e-12f);
    float y0 = x.x * inv, y1 = x.y * inv;
    u16 h0, l0, h1, l1;
    split_bf16(y0, h0, l0);
    split_bf16(y1, h1, l1);
    *(u32*)&F2[r * 256 + 2 * t]       = (u32)h0 | ((u32)h1 << 16);
    *(u32*)&F2[r * 256 + 128 + 2 * t] = (u32)l0 | ((u32)l1 << 16);
    *(float2*)&out[ptbase + rr * D + 2 * t] = x;   // exact bit copy
}

// ---------------------------------------------------------------------------
// prep_logits: transposed split-bf16 LT[pl][cls][key_permuted]; cls 100 = 1.0
// (folded softmax denominator). Key permutation within each 32-key window:
// logical key kl = t*16 + g*4 + r stored at column j = g*8 + r*2 + t so a
// wave's in-register P matches the 16x16x32 A-fragment slot order.
// pred_before via exact first-occurrence argmax.
// ---------------------------------------------------------------------------
__global__ void prep_logits(const float* __restrict__ l_lb,
                            const float* __restrict__ l_u1,
                            const float* __restrict__ l_u2,
                            u16* __restrict__ LT,
                            int* __restrict__ predB)
{
    const int r = blockIdx.x;
    const int t = threadIdx.x;   // 0..63
    const float* src; int rr;
    if (r < N_LB)              { src = l_lb; rr = r; }
    else if (r < N_LB + N_ULB) { src = l_u1; rr = r - N_LB; }
    else                       { src = l_u2; rr = r - N_LB - N_ULB; }
    // permuted storage column for key r
    const int pc = (r & ~31) | (((r >> 2) & 3) << 3) | ((r & 3) << 1) | ((r >> 4) & 1);
    float v0 = src[rr * C + t];
    const int c1 = t + 64;
    float v1 = (c1 < C) ? src[rr * C + c1] : 0.0f;
    u16 h, l;
    split_bf16(v0, h, l);
    LT[(size_t)(0 * CT + t) * N_TOT + pc] = h;
    LT[(size_t)(1 * CT + t) * N_TOT + pc] = l;
    if (c1 < CT) {
        float v = (c1 < C) ? v1 : ((c1 == C) ? 1.0f : 0.0f);
        split_bf16(v, h, l);
        LT[(size_t)(0 * CT + c1) * N_TOT + pc] = h;
        LT[(size_t)(1 * CT + c1) * N_TOT + pc] = l;
    }
    float bv = v0; int bi = t;
    if (c1 < C && v1 > bv) { bv = v1; bi = c1; }
    #pragma unroll
    for (int m = 32; m; m >>= 1) {
        float ov = __shfl_xor(bv, m);
        int   oi = __shfl_xor(bi, m);
        if (ov > bv || (ov == bv && oi < bi)) { bv = ov; bi = oi; }
    }
    if (t == 0) predB[r] = bi;
}

// ---------------------------------------------------------------------------
__global__ void copy_oh(const float4* __restrict__ oh, float4* __restrict__ out)
{
    for (int i = blockIdx.x * blockDim.x + threadIdx.x; i < N_LB * C / 4;
         i += gridDim.x * blockDim.x)
        out[i] = oh[i];
}

// ---------------------------------------------------------------------------
// attn_mfma round 11: fat-wave restructure. 256 threads = 4 waves, wave
// (mh in 2: 32 q) x (nqh in 2: 32 keys) owns a 32x32 tile -> each K row read
// by 2 waves (was 4), each L col by 2 (was 4): LDS reads halve (240->120 KB
// per chunk). All-x32 MFMA: S = 2 ktiles x 2 qtiles x 12; PV = 7ct x 3 x 2ms
// (per-wave 90 slots; per-SIMD unchanged). 1 wave/SIMD: ILP-only latency
// hiding (hoisted ds_reads + dbuf DMA). One barrier/chunk as before.
// ---------------------------------------------------------------------------
#define SK_BYTES  (64 * 512)     // key tile: 64 rows x [hi 256B | lo 256B]
#define SLT_BYTES (112 * 256)    // L^T tile: 112 cls x [hi 128B | lo 128B]

__launch_bounds__(256, 1)
__global__ void attn_mfma(const u16* __restrict__ F2, const u16* __restrict__ LT,
                          float* __restrict__ out)
{
    __shared__ __align__(16) char smem[2 * SK_BYTES + 2 * SLT_BYTES + 256];
    char* const sK0  = smem;
    char* const sK1  = smem + SK_BYTES;
    char* const sLT0 = smem + 2 * SK_BYTES;
    char* const sLT1 = smem + 2 * SK_BYTES + SLT_BYTES;
    float* const sInv = (float*)(smem + 2 * SK_BYTES + 2 * SLT_BYTES);

    const int tid  = threadIdx.x;
    const int lane = tid & 63;
    const int w    = tid >> 6;      // 0..3
    const int mh   = w >> 1;        // 32-q half
    const int nqh  = w & 1;         // 32-key window
    const int g    = lane >> 4;     // k-group
    const int lr   = lane & 15;
    const int r0   = blockIdx.x * 64;

    const char* F2b = (const char*)F2;
    const char* LTb = (const char*)LT;

    // zero-fill sLT class rows 104..111 (both buffers) once; never restaged
    {
        char* dst = (tid >> 7) ? sLT1 : sLT0;
        int row = 104 + ((tid & 127) >> 4), gr = tid & 15;
        *(f32x4*)(dst + row * 256 + gr * 16) = f32x4{0, 0, 0, 0};
    }

    // Q fragments (registers, hi/lo) for both 16-q subtiles of this mh-half
    short8 qhi[2][4], qlo[2][4];
    #pragma unroll
    for (int ms = 0; ms < 2; ++ms) {
        const char* base = F2b + (size_t)(r0 + mh * 32 + ms * 16 + lr) * 512;
        #pragma unroll
        for (int ks = 0; ks < 4; ++ks) {
            qhi[ms][ks] = *(const short8*)(base + ks * 64 + g * 16);
            qlo[ms][ks] = *(const short8*)(base + 256 + ks * 64 + g * 16);
        }
    }

    // ---- prologue: stage chunk 0 into buffer 0 ----
    #pragma unroll
    for (int it = 0; it < 8; ++it) {
        int idx = tid + it * 256;
        int row = idx >> 5, b = (idx & 31) << 4;
        gl_lds16(F2b + (size_t)row * 512 + (b ^ ((row & 15) << 4)), sK0 + idx * 16);
    }
    #pragma unroll
    for (int it = 0; it < 7; ++it) {
        int idx = tid + it * 256;
        if (idx < 1664) {
            int row = idx >> 4, b = (idx & 15) << 4;
            int b2 = b ^ ((row & 7) << 4);
            int pl = b2 >> 7, kb = b2 & 127;
            gl_lds16(LTb + ((size_t)(pl * CT + row) * N_TOT) * 2 + kb, sLT0 + idx * 16);
        }
    }

    f32x4 o[2][7];                  // [ms][cls-tile]; lane: cls=lr, q=g*4+reg
    #pragma unroll
    for (int ms = 0; ms < 2; ++ms)
        #pragma unroll
        for (int ct = 0; ct < 7; ++ct) o[ms][ct] = f32x4{0, 0, 0, 0};

    for (int ch = 0; ch < 256; ++ch) {
        const int cur = ch & 1;
        __syncthreads();   // drains own DMA (vmcnt 0): tile(ch) ready; other buf free

        // ---- issue async staging for chunk ch+1 ----
        if (ch + 1 < 256) {
            const int cn = (ch + 1) * 64;
            char* dK = cur ? sK0 : sK1;
            char* dL = cur ? sLT0 : sLT1;
            #pragma unroll
            for (int it = 0; it < 8; ++it) {
                int idx = tid + it * 256;
                int row = idx >> 5, b = (idx & 31) << 4;
                gl_lds16(F2b + (size_t)(cn + row) * 512 + (b ^ ((row & 15) << 4)),
                         dK + idx * 16);
            }
            #pragma unroll
            for (int it = 0; it < 7; ++it) {
                int idx = tid + it * 256;
                if (idx < 1664) {
                    int row = idx >> 4, b = (idx & 15) << 4;
                    int b2 = b ^ ((row & 7) << 4);
                    int pl = b2 >> 7, kb = b2 & 127;
                    gl_lds16(LTb + ((size_t)(pl * CT + row) * N_TOT + cn) * 2 + kb,
                             dL + idx * 16);
                }
            }
        }

        // ---- S = K.Q^T over 2 ktiles x 2 q-subtiles ----
        const char* K = cur ? sK1 : sK0;
        u16 h[2][2][4], l[2][2][4];   // [ms][t][reg]
        #pragma unroll
        for (int t = 0; t < 2; ++t) {
            const int krow = nqh * 32 + t * 16 + lr;
            const int sw = (krow & 15) << 4;
            short8 khi[4], klo[4];
            #pragma unroll
            for (int ks = 0; ks < 4; ++ks) {
                int bo = ks * 64 + g * 16;
                khi[ks] = *(const short8*)(K + krow * 512 + (bo ^ sw));
                klo[ks] = *(const short8*)(K + krow * 512 + ((256 + bo) ^ sw));
            }
            #pragma unroll
            for (int ms = 0; ms < 2; ++ms) {
                f32x4 acc = {0, 0, 0, 0};
                #pragma unroll
                for (int ks = 0; ks < 4; ++ks)
                    acc = __builtin_amdgcn_mfma_f32_16x16x32_bf16(khi[ks], qhi[ms][ks], acc, 0, 0, 0);
                #pragma unroll
                for (int ks = 0; ks < 4; ++ks)
                    acc = __builtin_amdgcn_mfma_f32_16x16x32_bf16(khi[ks], qlo[ms][ks], acc, 0, 0, 0);
                #pragma unroll
                for (int ks = 0; ks < 4; ++ks)
                    acc = __builtin_amdgcn_mfma_f32_16x16x32_bf16(klo[ks], qhi[ms][ks], acc, 0, 0, 0);
                #pragma unroll
                for (int reg = 0; reg < 4; ++reg) {
                    float p = __expf(10.0f * acc[reg] - 10.0f);
                    split_bf16(p, h[ms][t][reg], l[ms][t][reg]);
                }
            }
        }

        // ---- PV: o[ms][ct] += P(32 keys) . L^T, K=32 x32-MFMAs ----
        const char* Lt = cur ? sLT1 : sLT0;
        short8 Ahi[2], Alo[2];
        #pragma unroll
        for (int ms = 0; ms < 2; ++ms) {
            Ahi[ms] = short8{(short)h[ms][0][0], (short)h[ms][1][0],
                             (short)h[ms][0][1], (short)h[ms][1][1],
                             (short)h[ms][0][2], (short)h[ms][1][2],
                             (short)h[ms][0][3], (short)h[ms][1][3]};
            Alo[ms] = short8{(short)l[ms][0][0], (short)l[ms][1][0],
                             (short)l[ms][0][1], (short)l[ms][1][1],
                             (short)l[ms][0][2], (short)l[ms][1][2],
                             (short)l[ms][0][3], (short)l[ms][1][3]};
        }
        #pragma unroll
        for (int ct = 0; ct < 7; ++ct) {
            int cls = ct * 16 + lr;
            int swc = (cls & 7) << 4;
            int boh = (nqh * 64 + g * 16) ^ swc;        // hi plane (16B granule)
            int bol = 128 + boh;                        // lo plane
            short8 Bhi = *(const short8*)(Lt + cls * 256 + boh);
            short8 Blo = *(const short8*)(Lt + cls * 256 + bol);
            #pragma unroll
            for (int ms = 0; ms < 2; ++ms) {
                o[ms][ct] = __builtin_amdgcn_mfma_f32_16x16x32_bf16(Ahi[ms], Bhi, o[ms][ct], 0, 0, 0);
                o[ms][ct] = __builtin_amdgcn_mfma_f32_16x16x32_bf16(Ahi[ms], Blo, o[ms][ct], 0, 0, 0);
                o[ms][ct] = __builtin_amdgcn_mfma_f32_16x16x32_bf16(Alo[ms], Bhi, o[ms][ct], 0, 0, 0);
            }
        }
    }

    // ---- epilogue: 2-way nqh reduction, normalize, store ----
    __syncthreads();
    float* red = (float*)smem;      // 28 KB scratch, tiles dead now
    if (nqh == 1) {
        #pragma unroll
        for (int ms = 0; ms < 2; ++ms)
            #pragma unroll
            for (int ct = 0; ct < 7; ++ct)
                #pragma unroll
                for (int reg = 0; reg < 4; ++reg)
                    red[((mh * 2 + ms) * 7 + ct) * 256 + reg * 64 + lane] = o[ms][ct][reg];
    }
    __syncthreads();
    if (nqh == 0) {
        #pragma unroll
        for (int ms = 0; ms < 2; ++ms)
            #pragma unroll
            for (int ct = 0; ct < 7; ++ct)
                #pragma unroll
                for (int reg = 0; reg < 4; ++reg)
                    o[ms][ct][reg] += red[((mh * 2 + ms) * 7 + ct) * 256 + reg * 64 + lane];
        if (lr == 4) {              // cls 100 = ct 6, lr 4 -> denominator
            #pragma unroll
            for (int ms = 0; ms < 2; ++ms)
                #pragma unroll
                for (int reg = 0; reg < 4; ++reg)
                    sInv[mh * 32 + ms * 16 + g * 4 + reg] = 1.0f / o[ms][6][reg];
        }
    }
    __syncthreads();
    if (nqh == 0) {
        #pragma unroll
        for (int ms = 0; ms < 2; ++ms) {
            #pragma unroll
            for (int ct = 0; ct < 7; ++ct) {
                int cls = ct * 16 + lr;
                if (cls < C) {
                    #pragma unroll
                    for (int reg = 0; reg < 4; ++reg) {
                        int q = mh * 32 + ms * 16 + g * 4 + reg;
                        out[OFF_OUTLB + (size_t)(r0 + q) * C + cls] =
                            o[ms][ct][reg] * sInv[q];
                    }
                }
            }
        }
    }
}

// ---------------------------------------------------------------------------
__global__ void argmax_after(const float* __restrict__ LA, int* __restrict__ predA)
{
    const int lane = threadIdx.x & 63;
    const int row  = blockIdx.x * 4 + (threadIdx.x >> 6);
    float bv = LA[row * C + lane]; int bi = lane;
    const int c1 = lane + 64;
    if (c1 < C) { float v1 = LA[row * C + c1]; if (v1 > bv) { bv = v1; bi = c1; } }
    #pragma unroll
    for (int m = 32; m; m >>= 1) {
        float ov = __shfl_xor(bv, m);
        int   oi = __shfl_xor(bi, m);
        if (ov > bv || (ov == bv && oi < bi)) { bv = ov; bi = oi; }
    }
    if (lane == 0) predA[row] = bi;
}

// ---------------------------------------------------------------------------
__global__ void finalize(const int* __restrict__ predA, const int* __restrict__ predB,
                         float* __restrict__ out)
{
    __shared__ int sm[256];
    const int t = threadIdx.x;
    int local = N_TOT;
    for (int r = t; r < N_TOT; r += 256)
        if (predA[r] != predB[r] && r < local) local = r;
    sm[t] = local;
    __syncthreads();
    for (int s = 128; s; s >>= 1) {
        if (t < s) sm[t] = min(sm[t], sm[t + s]);
        __syncthreads();
    }
    if (t == 0) {
        int first = (sm[0] == N_TOT) ? 0 : sm[0];
        out[OFF_SCAL + 0] = (float)first;
        out[OFF_SCAL + 1] = (float)first;
        out[OFF_SCAL + 2] = (float)predB[first];
        out[OFF_SCAL + 3] = (float)predA[first];
        out[OFF_SCAL + 4] = (float)predB[first];
        out[OFF_SCAL + 5] = (float)predA[first];
    }
}

// ---------------------------------------------------------------------------
extern "C" void kernel_launch(void* const* d_in, const int* in_sizes, int n_in,
                              void* d_out, int out_size, void* d_ws, size_t ws_size,
                              hipStream_t stream)
{
    const float* anchor   = (const float*)d_in[0];
    const float* positive = (const float*)d_in[1];
    const float* lbf      = (const float*)d_in[2];
    const float* oh       = (const float*)d_in[3];
    const float* l_lb     = (const float*)d_in[4];
    const float* l_u1     = (const float*)d_in[5];
    const float* l_u2     = (const float*)d_in[6];
    float* out = (float*)d_out;

    u16* F2 = (u16*)d_ws;                            // 8 MB
    u16* LT = F2 + (size_t)N_TOT * 256;              // 6.8 MB
    int* predB = (int*)(LT + (size_t)2 * CT * N_TOT);
    int* predA = predB + N_TOT;

    prep_feats <<<N_TOT, 64, 0, stream>>>(anchor, positive, lbf, F2, out);
    prep_logits<<<N_TOT, 64, 0, stream>>>(l_lb, l_u1, l_u2, LT, predB);
    copy_oh    <<<200, 256, 0, stream>>>((const float4*)oh, (float4*)&out[OFF_OH]);
    attn_mfma  <<<256, 256, 0, stream>>>(F2, LT, out);
    argmax_after<<<N_TOT / 4, 256, 0, stream>>>(&out[OFF_OUTLB], predA);
    finalize   <<<1, 256, 0, stream>>>(predA, predB, out);
}

// Round 12
// 349.455 us; speedup vs baseline: 1.2821x; 1.2821x over previous
//
#include <hip/hip_runtime.h>
#include <hip/hip_bf16.h>

typedef unsigned short u16;
typedef unsigned int u32;
typedef __attribute__((ext_vector_type(8))) short short8;
typedef __attribute__((ext_vector_type(4))) float f32x4;

#define N_LB   4096
#define N_ULB  6144
#define N_TOT  16384
#define D      128
#define C      100
#define CT     104   // classes stored in LT (100 logits + denom@100 + 3 zero)
#define PSTR   104   // partials stride (cls 0..103)

// d_out element offsets (f32 elements, reference return order)
#define OFF_ANCHOR 0
#define OFF_POS    786432
#define OFF_LBF    1572864
#define OFF_OH     2097152
#define OFF_OUTLB  2506752   // out_lb / out_ulb_1 / out_ulb_2 row-contiguous
#define OFF_SCAL   4145152

__device__ __forceinline__ void split_bf16(float x, u16& hi, u16& lo) {
    __hip_bfloat16 h = __float2bfloat16(x);
    float r = x - __bfloat162float(h);
    __hip_bfloat16 l = __float2bfloat16(r);
    hi = __bfloat16_as_ushort(h);
    lo = __bfloat16_as_ushort(l);
}

// async global->LDS DMA, 16B per lane (wave-uniform LDS base + lane*16)
__device__ __forceinline__ void gl_lds16(const char* g, char* l) {
    __builtin_amdgcn_global_load_lds(
        (const __attribute__((address_space(1))) u32*)g,
        (__attribute__((address_space(3))) u32*)l, 16, 0, 0);
}

// ---------------------------------------------------------------------------
// prep_feats: L2-normalize rows; split to bf16 hi/lo planes in ws
// F2[16384][256] u16 (row = [hi 0..127 | lo 128..255]); exact f32 passthrough.
// ---------------------------------------------------------------------------
__global__ void prep_feats(const float* __restrict__ anchor,
                           const float* __restrict__ positive,
                           const float* __restrict__ lbf,
                           u16* __restrict__ F2,
                           float* __restrict__ out)
{
    const int r = blockIdx.x;
    const int t = threadIdx.x;   // 0..63
    const float* src; int rr, ptbase;
    if (r < N_LB)              { src = lbf;      rr = r;                ptbase = OFF_LBF; }
    else if (r < N_LB + N_ULB) { src = anchor;   rr = r - N_LB;         ptbase = OFF_ANCHOR; }
    else                       { src = positive; rr = r - N_LB - N_ULB; ptbase = OFF_POS; }
    float2 x = *(const float2*)&src[rr * D + 2 * t];
    float ss = x.x * x.x + x.y * x.y;
    #pragma unroll
    for (int m = 32; m; m >>= 1) ss += __shfl_xor(ss, m);
    float inv = 1.0f / fmaxf(sqrtf(ss), 1e-12f);
    float y0 = x.x * inv, y1 = x.y * inv;
    u16 h0, l0, h1, l1;
    split_bf16(y0, h0, l0);
    split_bf16(y1, h1, l1);
    *(u32*)&F2[r * 256 + 2 * t]       = (u32)h0 | ((u32)h1 << 16);
    *(u32*)&F2[r * 256 + 128 + 2 * t] = (u32)l0 | ((u32)l1 << 16);
    *(float2*)&out[ptbase + rr * D + 2 * t] = x;   // exact bit copy
}

// ---------------------------------------------------------------------------
// prep_logits: transposed split-bf16 LT[pl][cls][key_permuted]; cls 100 = 1.0
// (folded softmax denominator). Key permutation within each 32-key window:
// logical key kl = t*16 + g*4 + r stored at column j = g*8 + r*2 + t so a
// wave's in-register P matches the 16x16x32 A-fragment slot order.
// pred_before via exact first-occurrence argmax.
// ---------------------------------------------------------------------------
__global__ void prep_logits(const float* __restrict__ l_lb,
                            const float* __restrict__ l_u1,
                            const float* __restrict__ l_u2,
                            u16* __restrict__ LT,
                            int* __restrict__ predB)
{
    const int r = blockIdx.x;
    const int t = threadIdx.x;   // 0..63
    const float* src; int rr;
    if (r < N_LB)              { src = l_lb; rr = r; }
    else if (r < N_LB + N_ULB) { src = l_u1; rr = r - N_LB; }
    else                       { src = l_u2; rr = r - N_LB - N_ULB; }
    // permuted storage column for key r
    const int pc = (r & ~31) | (((r >> 2) & 3) << 3) | ((r & 3) << 1) | ((r >> 4) & 1);
    float v0 = src[rr * C + t];
    const int c1 = t + 64;
    float v1 = (c1 < C) ? src[rr * C + c1] : 0.0f;
    u16 h, l;
    split_bf16(v0, h, l);
    LT[(size_t)(0 * CT + t) * N_TOT + pc] = h;
    LT[(size_t)(1 * CT + t) * N_TOT + pc] = l;
    if (c1 < CT) {
        float v = (c1 < C) ? v1 : ((c1 == C) ? 1.0f : 0.0f);
        split_bf16(v, h, l);
        LT[(size_t)(0 * CT + c1) * N_TOT + pc] = h;
        LT[(size_t)(1 * CT + c1) * N_TOT + pc] = l;
    }
    float bv = v0; int bi = t;
    if (c1 < C && v1 > bv) { bv = v1; bi = c1; }
    #pragma unroll
    for (int m = 32; m; m >>= 1) {
        float ov = __shfl_xor(bv, m);
        int   oi = __shfl_xor(bi, m);
        if (ov > bv || (ov == bv && oi < bi)) { bv = ov; bi = oi; }
    }
    if (t == 0) predB[r] = bi;
}

// ---------------------------------------------------------------------------
__global__ void copy_oh(const float4* __restrict__ oh, float4* __restrict__ out)
{
    for (int i = blockIdx.x * blockDim.x + threadIdx.x; i < N_LB * C / 4;
         i += gridDim.x * blockDim.x)
        out[i] = oh[i];
}

// ---------------------------------------------------------------------------
// attn_mfma round 12: fat waves (32q x 32k, r11) + 2 waves/SIMD (r10's TLP).
// 256 blocks = (qb in 128: 128-q tile) x (kh in 2: 8192-key half); 512 thr =
// 8 waves (mq in 4) x (nqh in 2). Each block iterates its 128 chunks of 64
// keys; per-SIMD MFMA per chunk doubles vs r11 while LDS reads stay at the
// r10 level -> LDS:MFMA ratio 0.54 with 2-wave TLP to hide latency.
// Blocks write RAW partial sums (incl. folded denominator at cls 100) to
// parts[kh][q][104]; reduce_argmax sums kh halves, normalizes, writes out.
// ---------------------------------------------------------------------------
#define SK_BYTES  (64 * 512)     // key tile: 64 rows x [hi 256B | lo 256B]
#define SLT_BYTES (112 * 256)    // L^T tile: 112 cls x [hi 128B | lo 128B]

__launch_bounds__(512, 1)
__global__ void attn_mfma(const u16* __restrict__ F2, const u16* __restrict__ LT,
                          float* __restrict__ parts)
{
    __shared__ __align__(16) char smem[2 * SK_BYTES + 2 * SLT_BYTES];
    char* const sK0  = smem;
    char* const sK1  = smem + SK_BYTES;
    char* const sLT0 = smem + 2 * SK_BYTES;
    char* const sLT1 = smem + 2 * SK_BYTES + SLT_BYTES;

    const int tid  = threadIdx.x;
    const int lane = tid & 63;
    const int w    = tid >> 6;      // 0..7
    const int mq   = w >> 1;        // 32-q subtile of the 128-q block tile
    const int nqh  = w & 1;         // 32-key window of each 64-key chunk
    const int g    = lane >> 4;     // k-group
    const int lr   = lane & 15;
    const int kh   = blockIdx.x & 1;        // 8192-key half
    const int qb   = blockIdx.x >> 1;
    const int q0   = qb * 128;
    const int KB0  = kh * 8192;             // this block's key base

    const char* F2b = (const char*)F2;
    const char* LTb = (const char*)LT;

    // zero-fill sLT class rows 104..111 (both buffers) once; never restaged
    if (tid < 256) {
        char* dst = (tid >> 7) ? sLT1 : sLT0;
        int row = 104 + ((tid & 127) >> 4), gr = tid & 15;
        *(f32x4*)(dst + row * 256 + gr * 16) = f32x4{0, 0, 0, 0};
    }

    // Q fragments (registers, hi/lo) for both 16-q subtiles of this mq tile
    short8 qhi[2][4], qlo[2][4];
    #pragma unroll
    for (int ms = 0; ms < 2; ++ms) {
        const char* base = F2b + (size_t)(q0 + mq * 32 + ms * 16 + lr) * 512;
        #pragma unroll
        for (int ks = 0; ks < 4; ++ks) {
            qhi[ms][ks] = *(const short8*)(base + ks * 64 + g * 16);
            qlo[ms][ks] = *(const short8*)(base + 256 + ks * 64 + g * 16);
        }
    }

    // ---- prologue: stage chunk 0 (keys KB0..KB0+63) into buffer 0 ----
    #pragma unroll
    for (int it = 0; it < 4; ++it) {
        int idx = tid + it * 512;
        int row = idx >> 5, b = (idx & 31) << 4;
        gl_lds16(F2b + (size_t)(KB0 + row) * 512 + (b ^ ((row & 15) << 4)),
                 sK0 + idx * 16);
    }
    #pragma unroll
    for (int it = 0; it < 4; ++it) {
        int idx = tid + it * 512;
        if (idx < 1664) {
            int row = idx >> 4, b = (idx & 15) << 4;
            int b2 = b ^ ((row & 7) << 4);
            int pl = b2 >> 7, kb2 = b2 & 127;
            gl_lds16(LTb + ((size_t)(pl * CT + row) * N_TOT + KB0) * 2 + kb2,
                     sLT0 + idx * 16);
        }
    }

    f32x4 o[2][7];                  // [ms][cls-tile]; lane: cls=lr, q=g*4+reg
    #pragma unroll
    for (int ms = 0; ms < 2; ++ms)
        #pragma unroll
        for (int ct = 0; ct < 7; ++ct) o[ms][ct] = f32x4{0, 0, 0, 0};

    for (int ch = 0; ch < 128; ++ch) {
        const int cur = ch & 1;
        __syncthreads();   // drains own DMA (vmcnt 0): tile(ch) ready; other buf free

        // ---- issue async staging for chunk ch+1 ----
        if (ch + 1 < 128) {
            const int cn = KB0 + (ch + 1) * 64;
            char* dK = cur ? sK0 : sK1;
            char* dL = cur ? sLT0 : sLT1;
            #pragma unroll
            for (int it = 0; it < 4; ++it) {
                int idx = tid + it * 512;
                int row = idx >> 5, b = (idx & 31) << 4;
                gl_lds16(F2b + (size_t)(cn + row) * 512 + (b ^ ((row & 15) << 4)),
                         dK + idx * 16);
            }
            #pragma unroll
            for (int it = 0; it < 4; ++it) {
                int idx = tid + it * 512;
                if (idx < 1664) {
                    int row = idx >> 4, b = (idx & 15) << 4;
                    int b2 = b ^ ((row & 7) << 4);
                    int pl = b2 >> 7, kb2 = b2 & 127;
                    gl_lds16(LTb + ((size_t)(pl * CT + row) * N_TOT + cn) * 2 + kb2,
                             dL + idx * 16);
                }
            }
        }

        // ---- S = K.Q^T over 2 ktiles x 2 q-subtiles ----
        const char* K = cur ? sK1 : sK0;
        u16 h[2][2][4], l[2][2][4];   // [ms][t][reg]
        #pragma unroll
        for (int t = 0; t < 2; ++t) {
            const int krow = nqh * 32 + t * 16 + lr;
            const int sw = (krow & 15) << 4;
            short8 khi[4], klo[4];
            #pragma unroll
            for (int ks = 0; ks < 4; ++ks) {
                int bo = ks * 64 + g * 16;
                khi[ks] = *(const short8*)(K + krow * 512 + (bo ^ sw));
                klo[ks] = *(const short8*)(K + krow * 512 + ((256 + bo) ^ sw));
            }
            #pragma unroll
            for (int ms = 0; ms < 2; ++ms) {
                f32x4 acc = {0, 0, 0, 0};
                #pragma unroll
                for (int ks = 0; ks < 4; ++ks)
                    acc = __builtin_amdgcn_mfma_f32_16x16x32_bf16(khi[ks], qhi[ms][ks], acc, 0, 0, 0);
                #pragma unroll
                for (int ks = 0; ks < 4; ++ks)
                    acc = __builtin_amdgcn_mfma_f32_16x16x32_bf16(khi[ks], qlo[ms][ks], acc, 0, 0, 0);
                #pragma unroll
                for (int ks = 0; ks < 4; ++ks)
                    acc = __builtin_amdgcn_mfma_f32_16x16x32_bf16(klo[ks], qhi[ms][ks], acc, 0, 0, 0);
                #pragma unroll
                for (int reg = 0; reg < 4; ++reg) {
                    float p = __expf(10.0f * acc[reg] - 10.0f);
                    split_bf16(p, h[ms][t][reg], l[ms][t][reg]);
                }
            }
        }

        // ---- PV: o[ms][ct] += P(32 keys) . L^T, K=32 x32-MFMAs ----
        const char* Lt = cur ? sLT1 : sLT0;
        short8 Ahi[2], Alo[2];
        #pragma unroll
        for (int ms = 0; ms < 2; ++ms) {
            Ahi[ms] = short8{(short)h[ms][0][0], (short)h[ms][1][0],
                             (short)h[ms][0][1], (short)h[ms][1][1],
                             (short)h[ms][0][2], (short)h[ms][1][2],
                             (short)h[ms][0][3], (short)h[ms][1][3]};
            Alo[ms] = short8{(short)l[ms][0][0], (short)l[ms][1][0],
                             (short)l[ms][0][1], (short)l[ms][1][1],
                             (short)l[ms][0][2], (short)l[ms][1][2],
                             (short)l[ms][0][3], (short)l[ms][1][3]};
        }
        #pragma unroll
        for (int ct = 0; ct < 7; ++ct) {
            int cls = ct * 16 + lr;
            int swc = (cls & 7) << 4;
            int boh = (nqh * 64 + g * 16) ^ swc;        // hi plane (16B granule)
            int bol = 128 + boh;                        // lo plane
            short8 Bhi = *(const short8*)(Lt + cls * 256 + boh);
            short8 Blo = *(const short8*)(Lt + cls * 256 + bol);
            #pragma unroll
            for (int ms = 0; ms < 2; ++ms) {
                o[ms][ct] = __builtin_amdgcn_mfma_f32_16x16x32_bf16(Ahi[ms], Bhi, o[ms][ct], 0, 0, 0);
                o[ms][ct] = __builtin_amdgcn_mfma_f32_16x16x32_bf16(Ahi[ms], Blo, o[ms][ct], 0, 0, 0);
                o[ms][ct] = __builtin_amdgcn_mfma_f32_16x16x32_bf16(Alo[ms], Bhi, o[ms][ct], 0, 0, 0);
            }
        }
    }

    // ---- epilogue: 2-way nqh reduction in LDS, write raw partials ----
    __syncthreads();
    float* red = (float*)smem;      // 57 KB scratch, tiles dead now
    if (nqh == 1) {
        #pragma unroll
        for (int ms = 0; ms < 2; ++ms)
            #pragma unroll
            for (int ct = 0; ct < 7; ++ct)
                #pragma unroll
                for (int reg = 0; reg < 4; ++reg)
                    red[(((mq * 2 + ms) * 7) + ct) * 256 + reg * 64 + lane] = o[ms][ct][reg];
    }
    __syncthreads();
    if (nqh == 0) {
        #pragma unroll
        for (int ms = 0; ms < 2; ++ms) {
            #pragma unroll
            for (int ct = 0; ct < 7; ++ct) {
                int cls = ct * 16 + lr;
                if (cls < PSTR) {
                    #pragma unroll
                    for (int reg = 0; reg < 4; ++reg) {
                        int q = q0 + mq * 32 + ms * 16 + g * 4 + reg;
                        float v = o[ms][ct][reg] +
                                  red[(((mq * 2 + ms) * 7) + ct) * 256 + reg * 64 + lane];
                        parts[(size_t)(kh * N_TOT + q) * PSTR + cls] = v;
                    }
                }
            }
        }
    }
}

// ---------------------------------------------------------------------------
// reduce_argmax: sum kh partials, normalize by folded denominator (cls 100),
// write logits_after to d_out, and compute pred_after (first-occurrence).
// ---------------------------------------------------------------------------
__global__ void reduce_argmax(const float* __restrict__ parts,
                              float* __restrict__ out, int* __restrict__ predA)
{
    const int lane = threadIdx.x & 63;
    const int row  = blockIdx.x * 4 + (threadIdx.x >> 6);
    const float* p0 = parts + (size_t)row * PSTR;
    const float* p1 = parts + (size_t)(N_TOT + row) * PSTR;
    const float inv = 1.0f / (p0[100] + p1[100]);
    float v0 = (p0[lane] + p1[lane]) * inv;
    out[OFF_OUTLB + (size_t)row * C + lane] = v0;
    float bv = v0; int bi = lane;
    const int c1 = lane + 64;
    if (c1 < C) {
        float v1 = (p0[c1] + p1[c1]) * inv;
        out[OFF_OUTLB + (size_t)row * C + c1] = v1;
        if (v1 > bv) { bv = v1; bi = c1; }
    }
    #pragma unroll
    for (int m = 32; m; m >>= 1) {
        float ov = __shfl_xor(bv, m);
        int   oi = __shfl_xor(bi, m);
        if (ov > bv || (ov == bv && oi < bi)) { bv = ov; bi = oi; }
    }
    if (lane == 0) predA[row] = bi;
}

// ---------------------------------------------------------------------------
__global__ void finalize(const int* __restrict__ predA, const int* __restrict__ predB,
                         float* __restrict__ out)
{
    __shared__ int sm[256];
    const int t = threadIdx.x;
    int local = N_TOT;
    for (int r = t; r < N_TOT; r += 256)
        if (predA[r] != predB[r] && r < local) local = r;
    sm[t] = local;
    __syncthreads();
    for (int s = 128; s; s >>= 1) {
        if (t < s) sm[t] = min(sm[t], sm[t + s]);
        __syncthreads();
    }
    if (t == 0) {
        int first = (sm[0] == N_TOT) ? 0 : sm[0];
        out[OFF_SCAL + 0] = (float)first;
        out[OFF_SCAL + 1] = (float)first;
        out[OFF_SCAL + 2] = (float)predB[first];
        out[OFF_SCAL + 3] = (float)predA[first];
        out[OFF_SCAL + 4] = (float)predB[first];
        out[OFF_SCAL + 5] = (float)predA[first];
    }
}

// ---------------------------------------------------------------------------
extern "C" void kernel_launch(void* const* d_in, const int* in_sizes, int n_in,
                              void* d_out, int out_size, void* d_ws, size_t ws_size,
                              hipStream_t stream)
{
    const float* anchor   = (const float*)d_in[0];
    const float* positive = (const float*)d_in[1];
    const float* lbf      = (const float*)d_in[2];
    const float* oh       = (const float*)d_in[3];
    const float* l_lb     = (const float*)d_in[4];
    const float* l_u1     = (const float*)d_in[5];
    const float* l_u2     = (const float*)d_in[6];
    float* out = (float*)d_out;

    u16* F2 = (u16*)d_ws;                            // 8 MB
    u16* LT = F2 + (size_t)N_TOT * 256;              // 6.8 MB
    float* parts = (float*)(LT + (size_t)2 * CT * N_TOT);  // 13.6 MB
    int* predB = (int*)(parts + (size_t)2 * N_TOT * PSTR);
    int* predA = predB + N_TOT;

    prep_feats <<<N_TOT, 64, 0, stream>>>(anchor, positive, lbf, F2, out);
    prep_logits<<<N_TOT, 64, 0, stream>>>(l_lb, l_u1, l_u2, LT, predB);
    copy_oh    <<<200, 256, 0, stream>>>((const float4*)oh, (float4*)&out[OFF_OH]);
    attn_mfma  <<<256, 512, 0, stream>>>(F2, LT, parts);
    reduce_argmax<<<N_TOT / 4, 256, 0, stream>>>(parts, out, predA);
    finalize   <<<1, 256, 0, stream>>>(predA, predB, out);
}

// Round 13
// 343.318 us; speedup vs baseline: 1.3050x; 1.0179x over previous
//
#include <hip/hip_runtime.h>
#include <hip/hip_bf16.h>

typedef unsigned short u16;
typedef unsigned int u32;
typedef __attribute__((ext_vector_type(8))) short short8;
typedef __attribute__((ext_vector_type(4))) float f32x4;

#define N_LB   4096
#define N_ULB  6144
#define N_TOT  16384
#define D      128
#define C      100
#define CT     104   // classes stored in LT (100 logits + denom@100 + 3 zero)
#define PSTR   104   // partials stride (cls 0..103)

// d_out element offsets (f32 elements, reference return order)
#define OFF_ANCHOR 0
#define OFF_POS    786432
#define OFF_LBF    1572864
#define OFF_OH     2097152
#define OFF_OUTLB  2506752   // out_lb / out_ulb_1 / out_ulb_2 row-contiguous
#define OFF_SCAL   4145152

__device__ __forceinline__ void split_bf16(float x, u16& hi, u16& lo) {
    __hip_bfloat16 h = __float2bfloat16(x);
    float r = x - __bfloat162float(h);
    __hip_bfloat16 l = __float2bfloat16(r);
    hi = __bfloat16_as_ushort(h);
    lo = __bfloat16_as_ushort(l);
}

// async global->LDS DMA, 16B per lane (wave-uniform LDS base + lane*16)
__device__ __forceinline__ void gl_lds16(const char* g, char* l) {
    __builtin_amdgcn_global_load_lds(
        (const __attribute__((address_space(1))) u32*)g,
        (__attribute__((address_space(3))) u32*)l, 16, 0, 0);
}

// ---------------------------------------------------------------------------
// prep_all: fused feats + logits prep (one 64-thread wave per row r).
//  feats: L2-normalize row r, split to bf16 hi/lo planes in F2[16384][256];
//         exact f32 passthrough to d_out.
//  logits: transposed split-bf16 LT[pl][cls][key_permuted]; cls 100 = 1.0
//         (folded softmax denominator). Key permutation within each 32-key
//         window: logical key kl = t*16+g*4+r stored at col j = g*8+r*2+t so
//         a wave's in-register P matches the 16x16x32 A-fragment slot order.
//         pred_before via exact first-occurrence argmax.
// ---------------------------------------------------------------------------
__global__ void prep_all(const float* __restrict__ anchor,
                         const float* __restrict__ positive,
                         const float* __restrict__ lbf,
                         const float* __restrict__ l_lb,
                         const float* __restrict__ l_u1,
                         const float* __restrict__ l_u2,
                         u16* __restrict__ F2, u16* __restrict__ LT,
                         int* __restrict__ predB,
                         float* __restrict__ out)
{
    const int r = blockIdx.x;
    const int t = threadIdx.x;   // 0..63
    const float* fsrc; const float* lsrc; int rr, ptbase;
    if (r < N_LB)              { fsrc = lbf;      lsrc = l_lb; rr = r;                ptbase = OFF_LBF; }
    else if (r < N_LB + N_ULB) { fsrc = anchor;   lsrc = l_u1; rr = r - N_LB;         ptbase = OFF_ANCHOR; }
    else                       { fsrc = positive; lsrc = l_u2; rr = r - N_LB - N_ULB; ptbase = OFF_POS; }

    // ---- feats ----
    float2 x = *(const float2*)&fsrc[rr * D + 2 * t];
    float ss = x.x * x.x + x.y * x.y;
    #pragma unroll
    for (int m = 32; m; m >>= 1) ss += __shfl_xor(ss, m);
    float inv = 1.0f / fmaxf(sqrtf(ss), 1e-12f);
    u16 h0, l0, h1, l1;
    split_bf16(x.x * inv, h0, l0);
    split_bf16(x.y * inv, h1, l1);
    *(u32*)&F2[r * 256 + 2 * t]       = (u32)h0 | ((u32)h1 << 16);
    *(u32*)&F2[r * 256 + 128 + 2 * t] = (u32)l0 | ((u32)l1 << 16);
    *(float2*)&out[ptbase + rr * D + 2 * t] = x;   // exact bit copy

    // ---- logits ----
    const int pc = (r & ~31) | (((r >> 2) & 3) << 3) | ((r & 3) << 1) | ((r >> 4) & 1);
    float v0 = lsrc[rr * C + t];
    const int c1 = t + 64;
    float v1 = (c1 < C) ? lsrc[rr * C + c1] : 0.0f;
    u16 h, l;
    split_bf16(v0, h, l);
    LT[(size_t)(0 * CT + t) * N_TOT + pc] = h;
    LT[(size_t)(1 * CT + t) * N_TOT + pc] = l;
    if (c1 < CT) {
        float v = (c1 < C) ? v1 : ((c1 == C) ? 1.0f : 0.0f);
        split_bf16(v, h, l);
        LT[(size_t)(0 * CT + c1) * N_TOT + pc] = h;
        LT[(size_t)(1 * CT + c1) * N_TOT + pc] = l;
    }
    float bv = v0; int bi = t;
    if (c1 < C && v1 > bv) { bv = v1; bi = c1; }
    #pragma unroll
    for (int m = 32; m; m >>= 1) {
        float ov = __shfl_xor(bv, m);
        int   oi = __shfl_xor(bi, m);
        if (ov > bv || (ov == bv && oi < bi)) { bv = ov; bi = oi; }
    }
    if (t == 0) predB[r] = bi;
}

// ---------------------------------------------------------------------------
__global__ void copy_oh(const float4* __restrict__ oh, float4* __restrict__ out)
{
    for (int i = blockIdx.x * blockDim.x + threadIdx.x; i < N_LB * C / 4;
         i += gridDim.x * blockDim.x)
        out[i] = oh[i];
}

// ---------------------------------------------------------------------------
// attn_mfma round 13 = round 12 + T5 s_setprio around MFMA bursts.
// 256 blocks = (qb in 128: 128-q tile) x (kh in 2: 8192-key half); 512 thr =
// 8 fat waves (mq in 4 x nqh in 2), each owning 32q x 32keys -> 2 waves/SIMD.
// Per chunk: barrier (vmcnt0 = DMA deadline) | issue DMA(ch+1) | S (48 x32
// MFMA) | exp/split (prio 0) | PV (42 x32 MFMA). setprio(1) during MFMA
// bursts lets the CU scheduler feed the matrix pipe from the MFMA-ready wave
// while the sibling wave runs softmax VALU.
// ---------------------------------------------------------------------------
#define SK_BYTES  (64 * 512)     // key tile: 64 rows x [hi 256B | lo 256B]
#define SLT_BYTES (112 * 256)    // L^T tile: 112 cls x [hi 128B | lo 128B]

__launch_bounds__(512, 1)
__global__ void attn_mfma(const u16* __restrict__ F2, const u16* __restrict__ LT,
                          float* __restrict__ parts)
{
    __shared__ __align__(16) char smem[2 * SK_BYTES + 2 * SLT_BYTES];
    char* const sK0  = smem;
    char* const sK1  = smem + SK_BYTES;
    char* const sLT0 = smem + 2 * SK_BYTES;
    char* const sLT1 = smem + 2 * SK_BYTES + SLT_BYTES;

    const int tid  = threadIdx.x;
    const int lane = tid & 63;
    const int w    = tid >> 6;      // 0..7
    const int mq   = w >> 1;        // 32-q subtile of the 128-q block tile
    const int nqh  = w & 1;         // 32-key window of each 64-key chunk
    const int g    = lane >> 4;     // k-group
    const int lr   = lane & 15;
    const int kh   = blockIdx.x & 1;        // 8192-key half
    const int qb   = blockIdx.x >> 1;
    const int q0   = qb * 128;
    const int KB0  = kh * 8192;             // this block's key base

    const char* F2b = (const char*)F2;
    const char* LTb = (const char*)LT;

    // zero-fill sLT class rows 104..111 (both buffers) once; never restaged
    if (tid < 256) {
        char* dst = (tid >> 7) ? sLT1 : sLT0;
        int row = 104 + ((tid & 127) >> 4), gr = tid & 15;
        *(f32x4*)(dst + row * 256 + gr * 16) = f32x4{0, 0, 0, 0};
    }

    // Q fragments (registers, hi/lo) for both 16-q subtiles of this mq tile
    short8 qhi[2][4], qlo[2][4];
    #pragma unroll
    for (int ms = 0; ms < 2; ++ms) {
        const char* base = F2b + (size_t)(q0 + mq * 32 + ms * 16 + lr) * 512;
        #pragma unroll
        for (int ks = 0; ks < 4; ++ks) {
            qhi[ms][ks] = *(const short8*)(base + ks * 64 + g * 16);
            qlo[ms][ks] = *(const short8*)(base + 256 + ks * 64 + g * 16);
        }
    }

    // ---- prologue: stage chunk 0 (keys KB0..KB0+63) into buffer 0 ----
    #pragma unroll
    for (int it = 0; it < 4; ++it) {
        int idx = tid + it * 512;
        int row = idx >> 5, b = (idx & 31) << 4;
        gl_lds16(F2b + (size_t)(KB0 + row) * 512 + (b ^ ((row & 15) << 4)),
                 sK0 + idx * 16);
    }
    #pragma unroll
    for (int it = 0; it < 4; ++it) {
        int idx = tid + it * 512;
        if (idx < 1664) {
            int row = idx >> 4, b = (idx & 15) << 4;
            int b2 = b ^ ((row & 7) << 4);
            int pl = b2 >> 7, kb2 = b2 & 127;
            gl_lds16(LTb + ((size_t)(pl * CT + row) * N_TOT + KB0) * 2 + kb2,
                     sLT0 + idx * 16);
        }
    }

    f32x4 o[2][7];                  // [ms][cls-tile]; lane: cls=lr, q=g*4+reg
    #pragma unroll
    for (int ms = 0; ms < 2; ++ms)
        #pragma unroll
        for (int ct = 0; ct < 7; ++ct) o[ms][ct] = f32x4{0, 0, 0, 0};

    for (int ch = 0; ch < 128; ++ch) {
        const int cur = ch & 1;
        __syncthreads();   // drains own DMA (vmcnt 0): tile(ch) ready; other buf free

        // ---- issue async staging for chunk ch+1 ----
        if (ch + 1 < 128) {
            const int cn = KB0 + (ch + 1) * 64;
            char* dK = cur ? sK0 : sK1;
            char* dL = cur ? sLT0 : sLT1;
            #pragma unroll
            for (int it = 0; it < 4; ++it) {
                int idx = tid + it * 512;
                int row = idx >> 5, b = (idx & 31) << 4;
                gl_lds16(F2b + (size_t)(cn + row) * 512 + (b ^ ((row & 15) << 4)),
                         dK + idx * 16);
            }
            #pragma unroll
            for (int it = 0; it < 4; ++it) {
                int idx = tid + it * 512;
                if (idx < 1664) {
                    int row = idx >> 4, b = (idx & 15) << 4;
                    int b2 = b ^ ((row & 7) << 4);
                    int pl = b2 >> 7, kb2 = b2 & 127;
                    gl_lds16(LTb + ((size_t)(pl * CT + row) * N_TOT + cn) * 2 + kb2,
                             dL + idx * 16);
                }
            }
        }

        // ---- S = K.Q^T over 2 ktiles x 2 q-subtiles ----
        const char* K = cur ? sK1 : sK0;
        u16 h[2][2][4], l[2][2][4];   // [ms][t][reg]
        #pragma unroll
        for (int t = 0; t < 2; ++t) {
            const int krow = nqh * 32 + t * 16 + lr;
            const int sw = (krow & 15) << 4;
            short8 khi[4], klo[4];
            #pragma unroll
            for (int ks = 0; ks < 4; ++ks) {
                int bo = ks * 64 + g * 16;
                khi[ks] = *(const short8*)(K + krow * 512 + (bo ^ sw));
                klo[ks] = *(const short8*)(K + krow * 512 + ((256 + bo) ^ sw));
            }
            #pragma unroll
            for (int ms = 0; ms < 2; ++ms) {
                f32x4 acc = {0, 0, 0, 0};
                __builtin_amdgcn_s_setprio(1);
                #pragma unroll
                for (int ks = 0; ks < 4; ++ks)
                    acc = __builtin_amdgcn_mfma_f32_16x16x32_bf16(khi[ks], qhi[ms][ks], acc, 0, 0, 0);
                #pragma unroll
                for (int ks = 0; ks < 4; ++ks)
                    acc = __builtin_amdgcn_mfma_f32_16x16x32_bf16(khi[ks], qlo[ms][ks], acc, 0, 0, 0);
                #pragma unroll
                for (int ks = 0; ks < 4; ++ks)
                    acc = __builtin_amdgcn_mfma_f32_16x16x32_bf16(klo[ks], qhi[ms][ks], acc, 0, 0, 0);
                __builtin_amdgcn_s_setprio(0);
                #pragma unroll
                for (int reg = 0; reg < 4; ++reg) {
                    float p = __expf(10.0f * acc[reg] - 10.0f);
                    split_bf16(p, h[ms][t][reg], l[ms][t][reg]);
                }
            }
        }

        // ---- PV: o[ms][ct] += P(32 keys) . L^T, K=32 x32-MFMAs ----
        const char* Lt = cur ? sLT1 : sLT0;
        short8 Ahi[2], Alo[2];
        #pragma unroll
        for (int ms = 0; ms < 2; ++ms) {
            Ahi[ms] = short8{(short)h[ms][0][0], (short)h[ms][1][0],
                             (short)h[ms][0][1], (short)h[ms][1][1],
                             (short)h[ms][0][2], (short)h[ms][1][2],
                             (short)h[ms][0][3], (short)h[ms][1][3]};
            Alo[ms] = short8{(short)l[ms][0][0], (short)l[ms][1][0],
                             (short)l[ms][0][1], (short)l[ms][1][1],
                             (short)l[ms][0][2], (short)l[ms][1][2],
                             (short)l[ms][0][3], (short)l[ms][1][3]};
        }
        __builtin_amdgcn_s_setprio(1);
        #pragma unroll
        for (int ct = 0; ct < 7; ++ct) {
            int cls = ct * 16 + lr;
            int swc = (cls & 7) << 4;
            int boh = (nqh * 64 + g * 16) ^ swc;        // hi plane (16B granule)
            int bol = 128 + boh;                        // lo plane
            short8 Bhi = *(const short8*)(Lt + cls * 256 + boh);
            short8 Blo = *(const short8*)(Lt + cls * 256 + bol);
            #pragma unroll
            for (int ms = 0; ms < 2; ++ms) {
                o[ms][ct] = __builtin_amdgcn_mfma_f32_16x16x32_bf16(Ahi[ms], Bhi, o[ms][ct], 0, 0, 0);
                o[ms][ct] = __builtin_amdgcn_mfma_f32_16x16x32_bf16(Ahi[ms], Blo, o[ms][ct], 0, 0, 0);
                o[ms][ct] = __builtin_amdgcn_mfma_f32_16x16x32_bf16(Alo[ms], Bhi, o[ms][ct], 0, 0, 0);
            }
        }
        __builtin_amdgcn_s_setprio(0);
    }

    // ---- epilogue: 2-way nqh reduction in LDS, write raw partials ----
    __syncthreads();
    float* red = (float*)smem;      // 57 KB scratch, tiles dead now
    if (nqh == 1) {
        #pragma unroll
        for (int ms = 0; ms < 2; ++ms)
            #pragma unroll
            for (int ct = 0; ct < 7; ++ct)
                #pragma unroll
                for (int reg = 0; reg < 4; ++reg)
                    red[(((mq * 2 + ms) * 7) + ct) * 256 + reg * 64 + lane] = o[ms][ct][reg];
    }
    __syncthreads();
    if (nqh == 0) {
        #pragma unroll
        for (int ms = 0; ms < 2; ++ms) {
            #pragma unroll
            for (int ct = 0; ct < 7; ++ct) {
                int cls = ct * 16 + lr;
                if (cls < PSTR) {
                    #pragma unroll
                    for (int reg = 0; reg < 4; ++reg) {
                        int q = q0 + mq * 32 + ms * 16 + g * 4 + reg;
                        float v = o[ms][ct][reg] +
                                  red[(((mq * 2 + ms) * 7) + ct) * 256 + reg * 64 + lane];
                        parts[(size_t)(kh * N_TOT + q) * PSTR + cls] = v;
                    }
                }
            }
        }
    }
}

// ---------------------------------------------------------------------------
// reduce_argmax: sum kh partials, normalize by folded denominator (cls 100),
// write logits_after to d_out, and compute pred_after (first-occurrence).
// ---------------------------------------------------------------------------
__global__ void reduce_argmax(const float* __restrict__ parts,
                              float* __restrict__ out, int* __restrict__ predA)
{
    const int lane = threadIdx.x & 63;
    const int row  = blockIdx.x * 4 + (threadIdx.x >> 6);
    const float* p0 = parts + (size_t)row * PSTR;
    const float* p1 = parts + (size_t)(N_TOT + row) * PSTR;
    const float inv = 1.0f / (p0[100] + p1[100]);
    float v0 = (p0[lane] + p1[lane]) * inv;
    out[OFF_OUTLB + (size_t)row * C + lane] = v0;
    float bv = v0; int bi = lane;
    const int c1 = lane + 64;
    if (c1 < C) {
        float v1 = (p0[c1] + p1[c1]) * inv;
        out[OFF_OUTLB + (size_t)row * C + c1] = v1;
        if (v1 > bv) { bv = v1; bi = c1; }
    }
    #pragma unroll
    for (int m = 32; m; m >>= 1) {
        float ov = __shfl_xor(bv, m);
        int   oi = __shfl_xor(bi, m);
        if (ov > bv || (ov == bv && oi < bi)) { bv = ov; bi = oi; }
    }
    if (lane == 0) predA[row] = bi;
}

// ---------------------------------------------------------------------------
__global__ void finalize(const int* __restrict__ predA, const int* __restrict__ predB,
                         float* __restrict__ out)
{
    __shared__ int sm[256];
    const int t = threadIdx.x;
    int local = N_TOT;
    for (int r = t; r < N_TOT; r += 256)
        if (predA[r] != predB[r] && r < local) local = r;
    sm[t] = local;
    __syncthreads();
    for (int s = 128; s; s >>= 1) {
        if (t < s) sm[t] = min(sm[t], sm[t + s]);
        __syncthreads();
    }
    if (t == 0) {
        int first = (sm[0] == N_TOT) ? 0 : sm[0];
        out[OFF_SCAL + 0] = (float)first;
        out[OFF_SCAL + 1] = (float)first;
        out[OFF_SCAL + 2] = (float)predB[first];
        out[OFF_SCAL + 3] = (float)predA[first];
        out[OFF_SCAL + 4] = (float)predB[first];
        out[OFF_SCAL + 5] = (float)predA[first];
    }
}

// ---------------------------------------------------------------------------
extern "C" void kernel_launch(void* const* d_in, const int* in_sizes, int n_in,
                              void* d_out, int out_size, void* d_ws, size_t ws_size,
                              hipStream_t stream)
{
    const float* anchor   = (const float*)d_in[0];
    const float* positive = (const float*)d_in[1];
    const float* lbf      = (const float*)d_in[2];
    const float* oh       = (const float*)d_in[3];
    const float* l_lb     = (const float*)d_in[4];
    const float* l_u1     = (const float*)d_in[5];
    const float* l_u2     = (const float*)d_in[6];
    float* out = (float*)d_out;

    u16* F2 = (u16*)d_ws;                            // 8 MB
    u16* LT = F2 + (size_t)N_TOT * 256;              // 6.8 MB
    float* parts = (float*)(LT + (size_t)2 * CT * N_TOT);  // 13.6 MB
    int* predB = (int*)(parts + (size_t)2 * N_TOT * PSTR);
    int* predA = predB + N_TOT;

    prep_all  <<<N_TOT, 64, 0, stream>>>(anchor, positive, lbf, l_lb, l_u1, l_u2,
                                         F2, LT, predB, out);
    copy_oh   <<<200, 256, 0, stream>>>((const float4*)oh, (float4*)&out[OFF_OH]);
    attn_mfma <<<256, 512, 0, stream>>>(F2, LT, parts);
    reduce_argmax<<<N_TOT / 4, 256, 0, stream>>>(parts, out, predA);
    finalize  <<<1, 256, 0, stream>>>(predA, predB, out);
}